// Round 11
// baseline (112.455 us; speedup 1.0000x reference)
//
#include <hip/hip_runtime.h>

// Problem constants
#define BATCH 4
#define C_IN 128
#define HWD 56
#define L_PIX 3136
#define G_GRP 4
#define CG 32
#define D_DIM 288
#define NG 8
#define OG 32
#define NQ_SPL 72    // spline K-chunks: K = D*NG = 2304 = 72*32
#define NQ_BASE 9    // base   K-chunks: K = D = 288 = 9*32
#define L2E 1.44269504f
#define TWO_L2E 2.88539008f
#define XSTRIDE 233               // padded channel stride (233 % 4 == 1 -> dl groups at +8 banks)

typedef short  short8 __attribute__((ext_vector_type(8)));
typedef float  f32x4  __attribute__((ext_vector_type(4)));
typedef unsigned int u32x4 __attribute__((ext_vector_type(4)));

__device__ __forceinline__ unsigned int pack2(float lo, float hi) {
    unsigned short a = __builtin_bit_cast(unsigned short, (__bf16)lo);
    unsigned short b = __builtin_bit_cast(unsigned short, (__bf16)hi);
    return (unsigned int)a | ((unsigned int)b << 16);
}

// ---------------------------------------------------------------------------
// Prologue (verified r6/r7): coalesced read, bf16 convert, scatter to
// per-lane B-fragment order. K-permutation (must match main kernel A-gen):
//   spline: chunk q, lane dl, elem j  <->  d = 72*dl + q,      ng = j
//   base:   chunk q, lane dl, elem j  <->  d = 72*dl + 8*q + j
// ---------------------------------------------------------------------------
#define N_SPL_CHUNK (G_GRP * OG * D_DIM)         // 36864
#define N_BASE_CHUNK (G_GRP * OG * D_DIM / 8)    // 4608

__global__ __launch_bounds__(256) void convert_w_kernel(
    const float* __restrict__ spline_w,
    const float* __restrict__ base_w,
    short* __restrict__ wspl,
    short* __restrict__ wbase)
{
    int t = blockIdx.x * 256 + threadIdx.x;
    if (t >= N_SPL_CHUNK + N_BASE_CHUNK) return;
    if (t < N_SPL_CHUNK) {
        const f32x4* s4 = (const f32x4*)spline_w + (size_t)t * 2;  // coalesced
        f32x4 lo = s4[0], hi = s4[1];
        int flat = t * 8;
        int g = flat / (OG * D_DIM * NG);
        int r = flat - g * (OG * D_DIM * NG);
        int o = r / (D_DIM * NG);
        int d = (r - o * (D_DIM * NG)) >> 3;
        int dl = d / 72;
        int q  = d - dl * 72;
        int lane = dl * 16 + (o & 15);
        int ot = o >> 4;
        u32x4 pk;
        pk.x = pack2(lo.x, lo.y); pk.y = pack2(lo.z, lo.w);
        pk.z = pack2(hi.x, hi.y); pk.w = pack2(hi.z, hi.w);
        u32x4* dst = (u32x4*)wspl + (((size_t)(g * NQ_SPL + q) * 2 + ot) * 64 + lane);
        *dst = pk;
    } else {
        int tb = t - N_SPL_CHUNK;
        const f32x4* s4 = (const f32x4*)base_w + (size_t)tb * 2;   // coalesced
        f32x4 lo = s4[0], hi = s4[1];
        int flat = tb * 8;
        int g = flat / (OG * D_DIM);
        int r = flat - g * (OG * D_DIM);
        int o = r / D_DIM;
        int d0 = r - o * D_DIM;
        int dl = d0 / 72;
        int q  = (d0 - dl * 72) >> 3;
        int lane = dl * 16 + (o & 15);
        int ot = o >> 4;
        u32x4 pk;
        pk.x = pack2(lo.x, lo.y); pk.y = pack2(lo.z, lo.w);
        pk.z = pack2(hi.x, hi.y); pk.w = pack2(hi.z, hi.w);
        u32x4* dst = (u32x4*)wbase + (((size_t)(g * NQ_BASE + q) * 2 + ot) * 64 + lane);
        *dst = pk;
    }
}

// ---------------------------------------------------------------------------
// Main: 256 thr = 4 waves; block = one (b,g) x 64 pixels.
// Spline RBF via 2-exp recurrence: a=3.5(v+1); e_j=exp(-(a-j)^2);
//   reflect aa = flip ? 7-a : a (aa<=3.5), f_{k+1}=f_k*R*e^{-(2k+1)},
//   R=exp(2aa); e_j = flip ? f_{7-j} : f_j.  fminf clamp bounds f_k<=1
//   (no inf into MFMA; scrubs NaN via IEEE minNum).
// ---------------------------------------------------------------------------
__global__ __launch_bounds__(256, 3) void groupkan_mfma_kernel(
    const float* __restrict__ x,
    const float* __restrict__ base_b,
    const short* __restrict__ wspl,
    const short* __restrict__ wbase,
    float* __restrict__ out)
{
    __shared__ float xt[CG * XSTRIDE];   // per channel: 4 rows x 58 (+1 pad) = 29824 B

    const int tid  = threadIdx.x;
    const int tile = blockIdx.x;      // 0..48
    const int bg   = blockIdx.y;
    const int b = bg >> 2, g = bg & 3;
    const int l0 = tile * 64;
    const int y0 = l0 / HWD;

    // ---- stage x tile (zero-padded halo); 64-pixel tile spans <=2 rows ----
    const float* xg = x + (size_t)(b * C_IN + g * CG) * L_PIX;
    for (int e = tid; e < CG * 232; e += 256) {
        int c  = e / 232;
        int r  = e - c * 232;
        int ry = r / 58;
        int rx = r - ry * 58;
        int y  = y0 - 1 + ry;
        int xc = rx - 1;
        float v = 0.0f;
        if (y >= 0 && y < HWD && xc >= 0 && xc < HWD)
            v = xg[(size_t)c * L_PIX + y * HWD + xc];
        xt[c * XSTRIDE + r] = v;
    }
    __syncthreads();

    const int lane = tid & 63;
    const int wid  = tid >> 6;
    const int fr   = lane & 15;       // A-row (pixel) / B,D-col (channel)
    const int dl   = lane >> 4;       // this lane's d-range [72dl, 72dl+72)
    const int l    = l0 + wid * 16 + fr;
    const int yy   = l / HWD;
    const int xx   = l - yy * HWD;
    const int ybase = yy - y0;        // 0..1

    // per-lane LDS base; all chunk reads are compile-time offsets from P
    const float* P = xt + (dl * 8) * XSTRIDE + ybase * 58 + xx;

    f32x4 acc0, acc1;
    {
        float b0 = base_b[g * OG + fr];
        float b1 = base_b[g * OG + 16 + fr];
        acc0 = (f32x4){b0, b0, b0, b0};
        acc1 = (f32x4){b1, b1, b1, b1};
    }

    const short8* wl  = (const short8*)wspl + (size_t)g * NQ_SPL * 2 * 64 + lane;
    const short8* wbl = (const short8*)wbase + (size_t)g * NQ_BASE * 2 * 64 + lane;

    // ---- spline: chunk q=qo*9+qi -> lane's d = 72dl+q, c = 8dl+qo, kk = qi ----
    for (int qo = 0; qo < 8; ++qo) {
        const float* Pc = P + qo * XSTRIDE;
#pragma unroll
        for (int qi = 0; qi < 9; ++qi) {
            const int kh = qi / 3, kw = qi % 3;
            float v  = Pc[kh * 58 + kw];
            float a  = __builtin_fmaf(v, 3.5f, 3.5f);
            bool flip = a > 3.5f;
            float aa = flip ? 7.0f - a : a;       // aa <= 3.5
            float t  = (aa * L2E) * aa;
            float f0 = __builtin_amdgcn_exp2f(-t);            // exp(-aa^2)
            float R  = __builtin_amdgcn_exp2f(aa * TWO_L2E);  // exp(2aa) <= e^7
            float f1 = fminf((f0 * R) * 0.36787944f,   1.0f); // e^-1
            float f2 = fminf((f1 * R) * 0.049787068f,  1.0f); // e^-3
            float f3 = fminf((f2 * R) * 6.7379470e-3f, 1.0f); // e^-5
            float f4 = fminf((f3 * R) * 9.1188197e-4f, 1.0f); // e^-7
            float f5 = fminf((f4 * R) * 1.2340980e-4f, 1.0f); // e^-9
            float f6 = fminf((f5 * R) * 1.6701700e-5f, 1.0f); // e^-11
            float f7 = fminf((f6 * R) * 2.2603294e-6f, 1.0f); // e^-13
            float e0 = flip ? f7 : f0;
            float e1 = flip ? f6 : f1;
            float e2 = flip ? f5 : f2;
            float e3 = flip ? f4 : f3;
            float e4 = flip ? f3 : f4;
            float e5 = flip ? f2 : f5;
            float e6 = flip ? f1 : f6;
            float e7 = flip ? f0 : f7;
            u32x4 pk;
            pk.x = pack2(e0, e1); pk.y = pack2(e2, e3);
            pk.z = pack2(e4, e5); pk.w = pack2(e6, e7);
            short8 aF = __builtin_bit_cast(short8, pk);
            const int q = qo * 9 + qi;
            short8 bf0 = wl[(q * 2 + 0) * 64];
            short8 bf1 = wl[(q * 2 + 1) * 64];
            acc0 = __builtin_amdgcn_mfma_f32_16x16x32_bf16(aF, bf0, acc0, 0, 0, 0);
            acc1 = __builtin_amdgcn_mfma_f32_16x16x32_bf16(aF, bf1, acc1, 0, 0, 0);
        }
    }

    // ---- base: lane elem j -> d = 72dl+8q+j; silu(v) = v/(1+exp(-v)) ----
#pragma unroll
    for (int q = 0; q < 9; ++q) {
        float s0, s1, s2, s3, s4, s5, s6, s7;
#pragma unroll
        for (int j = 0; j < 8; ++j) {
            const int dd = 8 * q + j;             // 0..71
            const int co = dd / 9, kk = dd % 9;
            const int kh = kk / 3, kw = kk % 3;
            float v  = P[co * XSTRIDE + kh * 58 + kw];
            float ex = __builtin_amdgcn_exp2f(-(v * L2E));     // exp(-v)
            float s  = v * __builtin_amdgcn_rcpf(1.0f + ex);   // silu
            if (j == 0) s0 = s; else if (j == 1) s1 = s; else if (j == 2) s2 = s;
            else if (j == 3) s3 = s; else if (j == 4) s4 = s; else if (j == 5) s5 = s;
            else if (j == 6) s6 = s; else s7 = s;
        }
        u32x4 pk;
        pk.x = pack2(s0, s1); pk.y = pack2(s2, s3);
        pk.z = pack2(s4, s5); pk.w = pack2(s6, s7);
        short8 aF = __builtin_bit_cast(short8, pk);
        short8 bf0 = wbl[(q * 2 + 0) * 64];
        short8 bf1 = wbl[(q * 2 + 1) * 64];
        acc0 = __builtin_amdgcn_mfma_f32_16x16x32_bf16(aF, bf0, acc0, 0, 0, 0);
        acc1 = __builtin_amdgcn_mfma_f32_16x16x32_bf16(aF, bf1, acc1, 0, 0, 0);
    }

    // ---- store: D row=(dl*4+r) -> pixel, col=fr -> channel ----
    float* outp = out + (size_t)(b * C_IN + g * OG) * L_PIX;
    int pix = l0 + wid * 16 + dl * 4;
    *(f32x4*)(outp + (size_t)fr * L_PIX + pix)        = acc0;
    *(f32x4*)(outp + (size_t)(16 + fr) * L_PIX + pix) = acc1;
}

extern "C" void kernel_launch(void* const* d_in, const int* in_sizes, int n_in,
                              void* d_out, int out_size, void* d_ws, size_t ws_size,
                              hipStream_t stream) {
    const float* x        = (const float*)d_in[0];
    const float* spline_w = (const float*)d_in[1];
    const float* base_w   = (const float*)d_in[2];
    const float* base_b   = (const float*)d_in[3];
    float* out = (float*)d_out;

    short* wspl  = (short*)d_ws;                               // 294912 shorts
    short* wbase = wspl + (size_t)G_GRP * NQ_SPL * 2 * 64 * 8; //  36864 shorts

    int conv_threads = N_SPL_CHUNK + N_BASE_CHUNK;             // 41472
    convert_w_kernel<<<(conv_threads + 255) / 256, 256, 0, stream>>>(
        spline_w, base_w, wspl, wbase);

    dim3 grid(L_PIX / 64, BATCH * G_GRP);                      // 49 x 16
    groupkan_mfma_kernel<<<grid, 256, 0, stream>>>(x, base_b, wspl, wbase, out);
}

// Round 15
// 110.000 us; speedup vs baseline: 1.0223x; 1.0223x over previous
//
#include <hip/hip_runtime.h>

// Problem constants
#define BATCH 4
#define C_IN 128
#define HWD 56
#define L_PIX 3136
#define G_GRP 4
#define CG 32
#define D_DIM 288
#define NG 8
#define OG 32
#define NQ_SPL 72    // spline K-chunks: K = D*NG = 2304 = 72*32
#define NQ_BASE 9    // base   K-chunks: K = D = 288 = 9*32
#define L2E 1.44269504f
#define SQRT_L 1.2011224087f      // sqrt(log2 e)
#define A_SCL  4.2039284306f      // 3.5 * sqrt(log2 e)
#define XSTRIDE 233               // padded channel stride

typedef short  short8 __attribute__((ext_vector_type(8)));
typedef float  f32x4  __attribute__((ext_vector_type(4)));
typedef unsigned int u32x4 __attribute__((ext_vector_type(4)));

__device__ __forceinline__ unsigned int pack2(float lo, float hi) {
    unsigned short a = __builtin_bit_cast(unsigned short, (__bf16)lo);
    unsigned short b = __builtin_bit_cast(unsigned short, (__bf16)hi);
    return (unsigned int)a | ((unsigned int)b << 16);
}

// ---------------------------------------------------------------------------
// Prologue (verified r6/r7/r11): coalesced read, bf16 convert, scatter to
// per-lane B-fragment order. K-permutation (must match main kernel A-gen):
//   spline: chunk q, lane dl, elem j  <->  d = 72*dl + q,      ng = j
//   base:   chunk q, lane dl, elem j  <->  d = 72*dl + 8*q + j
// ---------------------------------------------------------------------------
#define N_SPL_CHUNK (G_GRP * OG * D_DIM)         // 36864
#define N_BASE_CHUNK (G_GRP * OG * D_DIM / 8)    // 4608

__global__ __launch_bounds__(256) void convert_w_kernel(
    const float* __restrict__ spline_w,
    const float* __restrict__ base_w,
    short* __restrict__ wspl,
    short* __restrict__ wbase)
{
    int t = blockIdx.x * 256 + threadIdx.x;
    if (t >= N_SPL_CHUNK + N_BASE_CHUNK) return;
    if (t < N_SPL_CHUNK) {
        const f32x4* s4 = (const f32x4*)spline_w + (size_t)t * 2;  // coalesced
        f32x4 lo = s4[0], hi = s4[1];
        int flat = t * 8;
        int g = flat / (OG * D_DIM * NG);
        int r = flat - g * (OG * D_DIM * NG);
        int o = r / (D_DIM * NG);
        int d = (r - o * (D_DIM * NG)) >> 3;
        int dl = d / 72;
        int q  = d - dl * 72;
        int lane = dl * 16 + (o & 15);
        int ot = o >> 4;
        u32x4 pk;
        pk.x = pack2(lo.x, lo.y); pk.y = pack2(lo.z, lo.w);
        pk.z = pack2(hi.x, hi.y); pk.w = pack2(hi.z, hi.w);
        u32x4* dst = (u32x4*)wspl + (((size_t)(g * NQ_SPL + q) * 2 + ot) * 64 + lane);
        *dst = pk;
    } else {
        int tb = t - N_SPL_CHUNK;
        const f32x4* s4 = (const f32x4*)base_w + (size_t)tb * 2;   // coalesced
        f32x4 lo = s4[0], hi = s4[1];
        int flat = tb * 8;
        int g = flat / (OG * D_DIM);
        int r = flat - g * (OG * D_DIM);
        int o = r / D_DIM;
        int d0 = r - o * D_DIM;
        int dl = d0 / 72;
        int q  = (d0 - dl * 72) >> 3;
        int lane = dl * 16 + (o & 15);
        int ot = o >> 4;
        u32x4 pk;
        pk.x = pack2(lo.x, lo.y); pk.y = pack2(lo.z, lo.w);
        pk.z = pack2(hi.x, hi.y); pk.w = pack2(hi.z, hi.w);
        u32x4* dst = (u32x4*)wbase + (((size_t)(g * NQ_BASE + q) * 2 + ot) * 64 + lane);
        *dst = pk;
    }
}

// ---------------------------------------------------------------------------
// Main: 256 thr = 4 waves; block = one (b,g) x 64 pixels.
// Spline RBF: 8 independent exp2's (r7 body — measured faster than the
// 2-exp serial recurrence, r11). B-fragment loads issued at TOP of each
// chunk so basis math covers their L2 latency (T14-lite).
// ---------------------------------------------------------------------------
__global__ __launch_bounds__(256, 3) void groupkan_mfma_kernel(
    const float* __restrict__ x,
    const float* __restrict__ base_b,
    const short* __restrict__ wspl,
    const short* __restrict__ wbase,
    float* __restrict__ out)
{
    __shared__ float xt[CG * XSTRIDE];   // per channel: 4 rows x 58 (+1 pad)

    const int tid  = threadIdx.x;
    const int tile = blockIdx.x;      // 0..48
    const int bg   = blockIdx.y;
    const int b = bg >> 2, g = bg & 3;
    const int l0 = tile * 64;
    const int y0 = l0 / HWD;

    // ---- stage x tile (zero-padded halo); 64-pixel tile spans <=2 rows ----
    const float* xg = x + (size_t)(b * C_IN + g * CG) * L_PIX;
    for (int e = tid; e < CG * 232; e += 256) {
        int c  = e / 232;
        int r  = e - c * 232;
        int ry = r / 58;
        int rx = r - ry * 58;
        int y  = y0 - 1 + ry;
        int xc = rx - 1;
        float v = 0.0f;
        if (y >= 0 && y < HWD && xc >= 0 && xc < HWD)
            v = xg[(size_t)c * L_PIX + y * HWD + xc];
        xt[c * XSTRIDE + r] = v;
    }
    __syncthreads();

    const int lane = tid & 63;
    const int wid  = tid >> 6;
    const int fr   = lane & 15;       // A-row (pixel) / B,D-col (channel)
    const int dl   = lane >> 4;       // this lane's d-range [72dl, 72dl+72)
    const int l    = l0 + wid * 16 + fr;
    const int yy   = l / HWD;
    const int xx   = l - yy * HWD;
    const int ybase = yy - y0;        // 0..1

    // per-lane LDS base; all chunk reads are compile-time offsets from P
    const float* P = xt + (dl * 8) * XSTRIDE + ybase * 58 + xx;

    f32x4 acc0, acc1;
    {
        float b0 = base_b[g * OG + fr];
        float b1 = base_b[g * OG + 16 + fr];
        acc0 = (f32x4){b0, b0, b0, b0};
        acc1 = (f32x4){b1, b1, b1, b1};
    }

    const short8* wl  = (const short8*)wspl + (size_t)g * NQ_SPL * 2 * 64 + lane;
    const short8* wbl = (const short8*)wbase + (size_t)g * NQ_BASE * 2 * 64 + lane;

    // ---- spline: chunk q=qo*9+qi -> lane's d = 72dl+q, c = 8dl+qo, kk = qi ----
    for (int qo = 0; qo < 8; ++qo) {
        const float* Pc = P + qo * XSTRIDE;
#pragma unroll
        for (int qi = 0; qi < 9; ++qi) {
            const int q = qo * 9 + qi;
            short8 bf0 = wl[(q * 2 + 0) * 64];    // issue loads FIRST
            short8 bf1 = wl[(q * 2 + 1) * 64];
            const int kh = qi / 3, kw = qi % 3;
            float v  = Pc[kh * 58 + kw];
            float ap = __builtin_fmaf(v, A_SCL, A_SCL);   // (v+1)*3.5*sqrt(log2e)
            float u;
            float e0, e1, e2, e3, e4, e5, e6, e7;
            u = ap - 0.0f * SQRT_L; e0 = __builtin_amdgcn_exp2f(-(u * u));
            u = ap - 1.0f * SQRT_L; e1 = __builtin_amdgcn_exp2f(-(u * u));
            u = ap - 2.0f * SQRT_L; e2 = __builtin_amdgcn_exp2f(-(u * u));
            u = ap - 3.0f * SQRT_L; e3 = __builtin_amdgcn_exp2f(-(u * u));
            u = ap - 4.0f * SQRT_L; e4 = __builtin_amdgcn_exp2f(-(u * u));
            u = ap - 5.0f * SQRT_L; e5 = __builtin_amdgcn_exp2f(-(u * u));
            u = ap - 6.0f * SQRT_L; e6 = __builtin_amdgcn_exp2f(-(u * u));
            u = ap - 7.0f * SQRT_L; e7 = __builtin_amdgcn_exp2f(-(u * u));
            u32x4 pk;
            pk.x = pack2(e0, e1); pk.y = pack2(e2, e3);
            pk.z = pack2(e4, e5); pk.w = pack2(e6, e7);
            short8 aF = __builtin_bit_cast(short8, pk);
            acc0 = __builtin_amdgcn_mfma_f32_16x16x32_bf16(aF, bf0, acc0, 0, 0, 0);
            acc1 = __builtin_amdgcn_mfma_f32_16x16x32_bf16(aF, bf1, acc1, 0, 0, 0);
        }
    }

    // ---- base: lane elem j -> d = 72dl+8q+j; silu(v) = v/(1+exp(-v)) ----
#pragma unroll
    for (int q = 0; q < 9; ++q) {
        short8 bf0 = wbl[(q * 2 + 0) * 64];       // issue loads FIRST
        short8 bf1 = wbl[(q * 2 + 1) * 64];
        float s0, s1, s2, s3, s4, s5, s6, s7;
#pragma unroll
        for (int j = 0; j < 8; ++j) {
            const int dd = 8 * q + j;             // 0..71
            const int co = dd / 9, kk = dd % 9;
            const int kh = kk / 3, kw = kk % 3;
            float v  = P[co * XSTRIDE + kh * 58 + kw];
            float ex = __builtin_amdgcn_exp2f(-(v * L2E));     // exp(-v)
            float s  = v * __builtin_amdgcn_rcpf(1.0f + ex);   // silu
            if (j == 0) s0 = s; else if (j == 1) s1 = s; else if (j == 2) s2 = s;
            else if (j == 3) s3 = s; else if (j == 4) s4 = s; else if (j == 5) s5 = s;
            else if (j == 6) s6 = s; else s7 = s;
        }
        u32x4 pk;
        pk.x = pack2(s0, s1); pk.y = pack2(s2, s3);
        pk.z = pack2(s4, s5); pk.w = pack2(s6, s7);
        short8 aF = __builtin_bit_cast(short8, pk);
        acc0 = __builtin_amdgcn_mfma_f32_16x16x32_bf16(aF, bf0, acc0, 0, 0, 0);
        acc1 = __builtin_amdgcn_mfma_f32_16x16x32_bf16(aF, bf1, acc1, 0, 0, 0);
    }

    // ---- store: D row=(dl*4+r) -> pixel, col=fr -> channel ----
    float* outp = out + (size_t)(b * C_IN + g * OG) * L_PIX;
    int pix = l0 + wid * 16 + dl * 4;
    *(f32x4*)(outp + (size_t)fr * L_PIX + pix)        = acc0;
    *(f32x4*)(outp + (size_t)(16 + fr) * L_PIX + pix) = acc1;
}

extern "C" void kernel_launch(void* const* d_in, const int* in_sizes, int n_in,
                              void* d_out, int out_size, void* d_ws, size_t ws_size,
                              hipStream_t stream) {
    const float* x        = (const float*)d_in[0];
    const float* spline_w = (const float*)d_in[1];
    const float* base_w   = (const float*)d_in[2];
    const float* base_b   = (const float*)d_in[3];
    float* out = (float*)d_out;

    short* wspl  = (short*)d_ws;                               // 294912 shorts
    short* wbase = wspl + (size_t)G_GRP * NQ_SPL * 2 * 64 * 8; //  36864 shorts

    int conv_threads = N_SPL_CHUNK + N_BASE_CHUNK;             // 41472
    convert_w_kernel<<<(conv_threads + 255) / 256, 256, 0, stream>>>(
        spline_w, base_w, wspl, wbase);

    dim3 grid(L_PIX / 64, BATCH * G_GRP);                      // 49 x 16
    groupkan_mfma_kernel<<<grid, 256, 0, stream>>>(x, base_b, wspl, wbase, out);
}